// Round 4
// baseline (438.572 us; speedup 1.0000x reference)
//
#include <hip/hip_runtime.h>
#include <hip/hip_bf16.h>
#include <math.h>

#define Hdim 512
#define Bdim 32
#define Sdim 2048
#define Kdim 1024            // 2*H
#define Mtot (Bdim * Sdim)   // 65536 rows

// scores GEMM v4: DRAM-page-locality fix.
// R0(BM=64) and R3(BM=128) both ran ~144 us = 256MB/1.78TB/s: K-sliced staging
// reads 256 B per 4-KB row per step -> ~16 page activations/row -> ~1.7 TB/s
// effective HBM (R2 measured 1.65 TB/s). Fix: stage full-row HALVES (2 KB
// contiguous per row-visit), ping-pong 64-KB LDS halves, one barrier per 8
// K-steps, persistent blocks (grid=256, 4 row-groups of 64 rows each).
#define RGROWS 64            // rows per row-group
#define HK 512               // K-floats per half
#define NSTEP 8              // K-steps (BK=64) per half
#define RGPB 4               // row-groups per block

typedef __attribute__((ext_vector_type(8))) short short8;
typedef __attribute__((ext_vector_type(4))) float floatx4;

// ---------------- fp32 -> bf16 (RNE) ----------------------------------------
__device__ __forceinline__ short f2bf(float f) {
    union { float f; unsigned u; } v; v.f = f;
    unsigned r = v.u + 0x7fffu + ((v.u >> 16) & 1u);
    return (short)(r >> 16);
}

// 8 fp32 -> 8 bf16 via packed converts
__device__ __forceinline__ short8 cvt8(float4 a, float4 b) {
    union { short8 s; __hip_bfloat162 h[4]; } u;
    u.h[0] = __float22bfloat162_rn(make_float2(a.x, a.y));
    u.h[1] = __float22bfloat162_rn(make_float2(a.z, a.w));
    u.h[2] = __float22bfloat162_rn(make_float2(b.x, b.y));
    u.h[3] = __float22bfloat162_rn(make_float2(b.z, b.w));
    return u.s;
}

__device__ __forceinline__ float fast_tanh(float x) {
    float ax = fabsf(x);
    float e  = __expf(-2.0f * ax);
    float r  = (1.0f - e) * __builtin_amdgcn_rcpf(1.0f + e);
    return copysignf(r, x);
}

// ---------------- Kernel 0: prep --------------------------------------------
// blocks 0..511: W_e fp32 [k][n] -> bf16 PACKED in MFMA-fragment order:
//   short8 index = (nt*32 + ks)*64 + lane,  lane = quad*16 + (n&15),
//   holding B[n = nt*16 + (n&15)][k = ks*32 + quad*8 .. +7].
// blocks 512..639: dec_proj = decoder_hide @ W_h + b_attn.
__global__ __launch_bounds__(256) void prep_kernel(
    const float* __restrict__ W_attn, const float* __restrict__ dec,
    const float* __restrict__ b_attn, short* __restrict__ Wbp,
    float* __restrict__ dec_proj)
{
    const int t = threadIdx.x;
    if (blockIdx.x < 512) {
        const float* We = W_attn + Hdim * Hdim;   // [1024][512]
        __shared__ short tile[32][33];            // [k_loc][n_loc]
        const int k0 = (blockIdx.x >> 4) * 32;
        const int n0 = (blockIdx.x & 15) * 32;
        const int r = t >> 5, c = t & 31;
        #pragma unroll
        for (int rr = 0; rr < 4; ++rr)
            tile[r + rr * 8][c] = f2bf(We[(size_t)(k0 + r + rr * 8) * Hdim + n0 + c]);
        __syncthreads();
        if (t < 128) {
            const int n_loc = t >> 2;             // 0..31
            const int q     = t & 3;              // quad = (k>>3)&3
            const int nt    = (n0 + n_loc) >> 4;
            const int lnn   = (n0 + n_loc) & 15;
            const int ks    = k0 >> 5;
            short8 v;
            #pragma unroll
            for (int r2 = 0; r2 < 8; ++r2) v[r2] = tile[q * 8 + r2][n_loc];
            ((short8*)Wbp)[((nt * 32 + ks) * 64) + q * 16 + lnn] = v;
        }
    } else {
        __shared__ float partl[2][128];
        const int bid = blockIdx.x - 512;      // 0..127
        const int b  = bid >> 2;
        const int cb = bid & 3;
        const int c  = cb * 128 + (t & 127);
        const int kh = t >> 7;
        float acc = 0.0f;
        const int kbeg = kh * 256, kend = kbeg + 256;
        #pragma unroll 8
        for (int k = kbeg; k < kend; ++k)
            acc = fmaf(dec[b * Hdim + k], W_attn[(size_t)k * Hdim + c], acc);
        partl[kh][t & 127] = acc;
        __syncthreads();
        if (t < 128)
            dec_proj[b * Hdim + cb * 128 + t] = partl[0][t] + partl[1][t] + b_attn[cb * 128 + t];
    }
}

// ---------------- Kernel 1: fused MFMA scores (panel-staged) ----------------
// Block = 512 thr / 8 waves, persistent over 4 row-groups of 64 rows.
// LDS: 2 half-panels [64 rows][512 k] bf16 (64 KB each), ping-pong.
// Per half h: [stage loads for h+1 issued at step 3] 8 K-steps of 64 from LDS
// (no barriers), then cvt+ds_write next half, ONE barrier. Staging reads are
// 2 KB contiguous per row (wave = one 2 KB burst) -> DRAM page friendly.
// LDS layout: row-major pitch 512 shorts; 16-B chunk c at slot c^(r&7)
// (2-way conflict-free on both b128 write and read phases).
__global__ __launch_bounds__(512, 2) void scores_kernel(
    const float* __restrict__ enc,      // [65536][1024] fp32
    const short* __restrict__ Wbp,      // packed B fragments (1 MB, L2-resident)
    const float* __restrict__ dec_proj, // [32][512]
    const float* __restrict__ v_w,      // [512]
    float* __restrict__ scores)         // [65536]
{
    __shared__ __align__(16) short Abuf[2][RGROWS * HK];  // 2 x 64 KB
    __shared__ float redl[RGROWS][9];                     // 2.3 KB

    const int t    = threadIdx.x;
    const int w    = t >> 6;             // wave 0..7 -> cols [64w, 64w+64)
    const int lane = t & 63;
    const int ln   = lane & 15;
    const int quad = lane >> 4;

    const int b = blockIdx.x >> 3;       // 8 blocks per batch (256 rows each)
    const float* Ablk = enc + (size_t)blockIdx.x * (RGPB * RGROWS) * Kdim;

    // ---- compute-side A frag addresses ----
    const int pf0 = (quad ^ (ln & 7)) * 8;   // phase 0 chunk slot (shorts)
    const int pf1 = pf0 ^ 32;                // phase 1 (chunk ^4)

    // ---- B packed per-lane base ----
    const short8* Bp = ((const short8*)Wbp) + lane;

    // ---- epilogue constants (loop-invariant) ----
    float dpv[4], vwv[4];
    #pragma unroll
    for (int j = 0; j < 4; ++j) {
        const int col = w * 64 + j * 16 + ln;
        dpv[j] = dec_proj[b * Hdim + col];
        vwv[j] = v_w[col];
    }

    floatx4 acc[4][4];
    #pragma unroll
    for (int i = 0; i < 4; ++i)
        #pragma unroll
        for (int j = 0; j < 4; ++j)
            acc[i][j] = (floatx4)(0.0f);

    float4 stage[16];

    // issue HBM loads for half hh (row-contiguous 2 KB bursts per wave-iter)
    #define ISSUE(hh) do {                                                    \
        const float* p_ = Ablk + (size_t)((hh) >> 1) * RGROWS * Kdim          \
                         + ((hh) & 1) * HK + lane * 8;                        \
        _Pragma("unroll")                                                     \
        for (int j_ = 0; j_ < 8; ++j_) {                                      \
            const float4* g_ = (const float4*)(p_ + (size_t)(j_ * 8 + w) * Kdim); \
            stage[2 * j_]     = g_[0];                                        \
            stage[2 * j_ + 1] = g_[1];                                        \
        }                                                                     \
    } while (0)

    // cvt + swizzled LDS write of staged half into buffer bi_
    #define WRITEHALF(bi_) do {                                               \
        _Pragma("unroll")                                                     \
        for (int j_ = 0; j_ < 8; ++j_) {                                      \
            const int r_ = j_ * 8 + w;                                        \
            *(short8*)&Abuf[bi_][r_ * HK + ((lane ^ (r_ & 7)) << 3)] =        \
                cvt8(stage[2 * j_], stage[2 * j_ + 1]);                       \
        }                                                                     \
    } while (0)

    // ---- prologue: stage half 0 into buf 0 ----
    ISSUE(0);
    WRITEHALF(0);
    __syncthreads();

    #pragma unroll 1
    for (int h = 0; h < 2 * RGPB; ++h) {
        const int bi  = h & 1;
        const short* Ab = Abuf[bi];
        const int ksb = (h & 1) * 16;        // global k-slice base of this half

        #pragma unroll
        for (int s = 0; s < NSTEP; ++s) {
            const int ks = ksb + 2 * s;
            short8 b0[4], b1[4];
            #pragma unroll
            for (int j = 0; j < 4; ++j)
                b0[j] = Bp[((size_t)(w * 4 + j) * 32 + ks) * 64];
            #pragma unroll
            for (int j = 0; j < 4; ++j)
                b1[j] = Bp[((size_t)(w * 4 + j) * 32 + ks + 1) * 64];

            if (s == 3 && h < 2 * RGPB - 1) ISSUE(h + 1);  // HBM loads in flight

            short8 af[4];
            #pragma unroll
            for (int i2 = 0; i2 < 4; ++i2)
                af[i2] = *(const short8*)&Ab[(i2 * 16 + ln) * HK + s * 64 + pf0];
            #pragma unroll
            for (int i2 = 0; i2 < 4; ++i2)
                #pragma unroll
                for (int j = 0; j < 4; ++j)
                    acc[i2][j] = __builtin_amdgcn_mfma_f32_16x16x32_bf16(
                                     af[i2], b0[j], acc[i2][j], 0, 0, 0);
            #pragma unroll
            for (int i2 = 0; i2 < 4; ++i2)
                af[i2] = *(const short8*)&Ab[(i2 * 16 + ln) * HK + s * 64 + pf1];
            #pragma unroll
            for (int i2 = 0; i2 < 4; ++i2)
                #pragma unroll
                for (int j = 0; j < 4; ++j)
                    acc[i2][j] = __builtin_amdgcn_mfma_f32_16x16x32_bf16(
                                     af[i2], b1[j], acc[i2][j], 0, 0, 0);
        }

        if (h & 1) {
            // ---- epilogue for row-group rg = h>>1 ----
            const int rg = h >> 1;
            #pragma unroll
            for (int i2 = 0; i2 < 4; ++i2) {
                #pragma unroll
                for (int reg = 0; reg < 4; ++reg) {
                    float s2 = 0.0f;
                    #pragma unroll
                    for (int j = 0; j < 4; ++j) {
                        float x = acc[i2][j][reg] + dpv[j];
                        s2 = fmaf(vwv[j], fast_tanh(x), s2);
                    }
                    s2 += __shfl_xor(s2, 1, 64);
                    s2 += __shfl_xor(s2, 2, 64);
                    s2 += __shfl_xor(s2, 4, 64);
                    s2 += __shfl_xor(s2, 8, 64);
                    if (ln == 0)
                        redl[i2 * 16 + quad * 4 + reg][w] = s2;
                }
            }
            __syncthreads();
            if (t < RGROWS) {
                float s2 = 0.0f;
                #pragma unroll
                for (int wv = 0; wv < 8; ++wv) s2 += redl[t][wv];
                scores[blockIdx.x * (RGPB * RGROWS) + rg * RGROWS + t] = s2;
            }
            #pragma unroll
            for (int i = 0; i < 4; ++i)
                #pragma unroll
                for (int j = 0; j < 4; ++j)
                    acc[i][j] = (floatx4)(0.0f);
        }

        if (h < 2 * RGPB - 1) WRITEHALF(bi ^ 1);
        __syncthreads();
    }
    #undef ISSUE
    #undef WRITEHALF
}

// ---------------- Kernel 2: masked softmax over S per batch -----------------
__global__ __launch_bounds__(256) void softmax_kernel(
    const float* __restrict__ scores, const int* __restrict__ mask,
    float* __restrict__ out)
{
    __shared__ float sred[8];
    const int b = blockIdx.x;
    const int t = threadIdx.x;
    const int lane = t & 63;
    const int wid  = t >> 6;

    float x[8];
    float m = -1e30f;
    #pragma unroll
    for (int j = 0; j < 8; ++j) {
        int idx = b * Sdim + j * 256 + t;
        float v = scores[idx];
        if (mask[idx] == 0) v = -100000.0f;
        x[j] = v;
        m = fmaxf(m, v);
    }
    #pragma unroll
    for (int off = 32; off >= 1; off >>= 1)
        m = fmaxf(m, __shfl_xor(m, off, 64));
    if (lane == 0) sred[wid] = m;
    __syncthreads();
    m = fmaxf(fmaxf(sred[0], sred[1]), fmaxf(sred[2], sred[3]));

    float s = 0.0f;
    #pragma unroll
    for (int j = 0; j < 8; ++j) {
        float e = __expf(x[j] - m);
        x[j] = e;
        s += e;
    }
    #pragma unroll
    for (int off = 32; off >= 1; off >>= 1)
        s += __shfl_xor(s, off, 64);
    if (lane == 0) sred[4 + wid] = s;
    __syncthreads();
    s = sred[4] + sred[5] + sred[6] + sred[7];

    const float inv = 1.0f / s;
    #pragma unroll
    for (int j = 0; j < 8; ++j)
        out[b * Sdim + j * 256 + t] = x[j] * inv;
}

// ---------------- launch ----------------------------------------------------
extern "C" void kernel_launch(void* const* d_in, const int* in_sizes, int n_in,
                              void* d_out, int out_size, void* d_ws, size_t ws_size,
                              hipStream_t stream) {
    const float* dec  = (const float*)d_in[0];   // (B, H)
    const float* enc  = (const float*)d_in[1];   // (B, S, 2H)
    const int*   mask = (const int*)  d_in[2];   // (B, S)
    const float* W    = (const float*)d_in[3];   // (3H, H)
    const float* ba   = (const float*)d_in[4];   // (H,)
    const float* vw   = (const float*)d_in[5];   // (H,)
    float* out = (float*)d_out;                  // (B, S)

    // workspace layout (~1.3 MB)
    float* dec_proj = (float*)d_ws;                       // 32*512 f   = 64 KB
    short* Wbp      = (short*)(dec_proj + Bdim * Hdim);   // 512*1024 s = 1 MB (packed)
    float* scores   = (float*)(Wbp + Hdim * Kdim);        // 65536 f    = 256 KB

    prep_kernel<<<640, 256, 0, stream>>>(W, dec, ba, Wbp, dec_proj);
    scores_kernel<<<Mtot / (RGPB * RGROWS), 512, 0, stream>>>(enc, Wbp, dec_proj, vw, scores);
    softmax_kernel<<<Bdim, 256, 0, stream>>>(scores, mask, out);
}